// Round 24
// baseline (236.639 us; speedup 1.0000x reference)
//
#include <hip/hip_runtime.h>
#include <hip/hip_fp16.h>

// ---------------------------------------------------------------------------
// Round 24: r23 + epilogue transcendental cut.
// r23 VALU decomposition: epilogue ~45% of per-wave issue (96 trans ops at
// 4-8cy on the quarter-rate trans pipe). Cuts:
//   1. shared-rcp: R = rcp(A*B); 1/A = R*B, 1/B = R*A  (-16 rcp/wave)
//   2. fold 5*tanh - a:  ex = (5-ax) - 10/A, c1 hoisted per-lane
//   3. launch_bounds(512,8) hint (VGPR 48 <= 64 budget, free)
// Everything else identical to r23 (zero-mov B-frag, LDS-staged weights).
// ---------------------------------------------------------------------------

typedef _Float16 f16x8 __attribute__((ext_vector_type(8)));
typedef __fp16 fp16x2 __attribute__((ext_vector_type(2)));
typedef float f32x16 __attribute__((ext_vector_type(16)));
typedef unsigned u32x2 __attribute__((ext_vector_type(2)));

// half-index offsets inside ws / LDS
#define OFF_G1 0        // [stream 0..1][tile 0..3][lane 0..63][j 0..7]
#define OFF_WV 4096     // [kt 0..6][lane][j]
#define OFF_WC 7680     // [T 0..1][kt 0..6][lane][j]
#define TOT_HALVES 14848 // 29696 bytes

// pack two f32 -> 2xf16 (RTZ) then packed relu (v_pk_max_f16)
__device__ __forceinline__ unsigned pkrtz_relu(float a, float b) {
    fp16x2 v = __builtin_amdgcn_cvt_pkrtz(a, b);
    fp16x2 z = {(__fp16)0.f, (__fp16)0.f};
    fp16x2 r = __builtin_elementwise_max(v, z);
    union { fp16x2 v; unsigned u; } U;
    U.v = r;
    return U.u;
}
__device__ __forceinline__ unsigned pk_rne(float a, float b) {
    union { __half h[2]; unsigned u; } U;
    U.h[0] = __float2half(a);
    U.h[1] = __float2half(b);
    return U.u;
}

// ---------------- prologue: build fragment-layout weights in ws (f16) ------
__global__ __launch_bounds__(256) void prep_kernel(
    const float* __restrict__ W1, const float* __restrict__ b1,
    const float* __restrict__ W2, const float* __restrict__ b2,
    const float* __restrict__ L1, const float* __restrict__ bl1,
    const float* __restrict__ WL2, const float* __restrict__ bL2,
    unsigned short* __restrict__ ws)
{
    int idx = blockIdx.x * 256 + threadIdx.x;
    if (idx >= TOT_HALVES) return;
    float val = 0.f;

    if (idx < OFF_WV) {
        // GEMM1'' A: [r][t][ln][j]; row c = 32t + (ln&31), k = (ln>>5)*8+j
        int r = idx >> 11, t = (idx >> 9) & 3;
        int ln = (idx >> 3) & 63, j = idx & 7;
        int c = 32 * t + (ln & 31);
        int k = (ln >> 5) * 8 + j;
        const float* W  = (r == 0) ? W1 : L1;
        const float* bb = (r == 0) ? b1 : bl1;
        if (c < 100)       val = (k < 10) ? W[k * 100 + c] : ((k == 10) ? bb[c] : 0.f);
        else if (c == 100) val = (k == 10) ? 1.f : 0.f;    // h[100]=1 bias unit
    } else if (idx < OFF_WC) {
        // GEMM2'' value A: row v -> n = (v&0x19)|((v&4)>>1)|((v&2)<<1)
        // k-slot relabel: j -> pj = (j&1)|((j&2)<<1)|((j&4)>>1)
        int i = idx - OFF_WV;
        int kt = i >> 9, ln = (i >> 3) & 63, j = i & 7;
        int pj = (j & 1) | ((j & 2) << 1) | ((j & 4) >> 1);
        int v = ln & 31;
        int n = (v & 0x19) | ((v & 4) >> 1) | ((v & 2) << 1);
        int k = kt * 16 + (ln >> 5) * 8 + pj;
        if (n < 30) val = (k < 100) ? W2[k * 30 + n] : ((k == 100) ? b2[n] : 0.f);
    } else {
        // GEMM2'' centroid A: [T][kt][ln][j]; row -> (n = 16T + row>>1, d = row&1)
        int i = idx - OFF_WC;
        int T = i / 3584, rem = i % 3584;
        int kt = rem >> 9, ln = (rem >> 3) & 63, j = rem & 7;
        int pj = (j & 1) | ((j & 2) << 1) | ((j & 4) >> 1);
        int row = ln & 31;
        int n = 16 * T + (row >> 1), d = row & 1;
        int k = kt * 16 + (ln >> 5) * 8 + pj;
        if (n < 30) val = (k < 100) ? WL2[(n * 100 + k) * 2 + d]
                                    : ((k == 100) ? bL2[n * 2 + d] : 0.f);
    }
    union { __half h; unsigned short u; } cv;
    cv.h = __float2half(val);            // RNE
    ws[idx] = cv.u;
}

// ---------------- main fused kernel (LDS-staged weights, 512 thr) ----------
__global__ __launch_bounds__(512, 8) void fused_kernel(
    const float* __restrict__ s, const float* __restrict__ a,
    const unsigned short* __restrict__ ws, float* __restrict__ out)
{
    __shared__ unsigned short lds[TOT_HALVES];
    const int tid  = threadIdx.x;
    const int lane = tid & 63;
    const int wave = tid >> 6;             // 0..7
    const int m32  = lane & 31;
    const int hi   = lane >> 5;
    const int sample = blockIdx.x * 256 + wave * 32 + m32;

    // ---- stage ws -> LDS (16B chunks, 4 iters) + barrier -------------------
    {
        const int4* g4 = (const int4*)ws;
        int4* l4 = (int4*)lds;
        for (int i = tid; i < TOT_HALVES / 8; i += 512) l4[i] = g4[i];
    }

    union Frag { f16x8 v; unsigned u[4]; u32x2 p[2]; };
    const f32x16 z16 = {0,0,0,0, 0,0,0,0, 0,0,0,0, 0,0,0,0};

    // ---- s^T B-frag (overlaps staging latency): col = m32, k = hi*8+j ------
    f16x8 sf;
    {
        Frag H;
        H.u[0] = 0; H.u[1] = 0; H.u[2] = 0; H.u[3] = 0;
        const float2* p = (const float2*)(s + (size_t)sample * 10);
        if (hi == 0) {
            float2 q0 = p[0], q1 = p[1], q2 = p[2], q3 = p[3];
            H.u[0] = pk_rne(q0.x, q0.y);
            H.u[1] = pk_rne(q1.x, q1.y);
            H.u[2] = pk_rne(q2.x, q2.y);
            H.u[3] = pk_rne(q3.x, q3.y);
        } else {
            float2 q4 = p[4];
            H.u[0] = pk_rne(q4.x, q4.y);     // k = 8, 9
            H.u[1] = 0x00003C00u;            // k = 10 -> f16 1.0 (bias row)
        }
        sf = H.v;
    }
    // prefetch a for the epilogue (hide HBM latency under the body)
    float2 av = ((const float2*)a)[sample];

    __syncthreads();

    f32x16 DV = z16, DC0 = z16, DC1 = z16;

    #pragma unroll
    for (int t = 0; t < 4; ++t) {
        // ---- GEMM1'' tile t, both streams (LDS b128 reads) -----------------
        f16x8 aV = *(const f16x8*)(lds + OFF_G1 + (0 * 4 + t) * 512 + lane * 8);
        f16x8 aH = *(const f16x8*)(lds + OFF_G1 + (1 * 4 + t) * 512 + lane * 8);
        f32x16 dv = __builtin_amdgcn_mfma_f32_32x32x16_f16(aV, sf, z16, 0, 0, 0);
        f32x16 dh = __builtin_amdgcn_mfma_f32_32x32x16_f16(aH, sf, z16, 0, 0, 0);

        unsigned qv[8], qh[8];
        #pragma unroll
        for (int q = 0; q < 8; ++q) {
            qv[q] = pkrtz_relu(dv[2 * q], dv[2 * q + 1]);
            qh[q] = pkrtz_relu(dh[2 * q], dh[2 * q + 1]);
        }

        // ---- consume kt = 2t (+1): permlane exchange + GEMM2'' -------------
        // B-frag = concat(sv0, sv1): zero-mov (weights k-relabeled in prep)
        #pragma unroll
        for (int half = 0; half < 2; ++half) {
            const int kt = 2 * t + half;
            if (kt < 7) {
                const int b = half * 4;
                Frag BV, BH;
                BV.p[0] = __builtin_amdgcn_permlane32_swap(qv[b+0], qv[b+2], false, false);
                BV.p[1] = __builtin_amdgcn_permlane32_swap(qv[b+1], qv[b+3], false, false);
                BH.p[0] = __builtin_amdgcn_permlane32_swap(qh[b+0], qh[b+2], false, false);
                BH.p[1] = __builtin_amdgcn_permlane32_swap(qh[b+1], qh[b+3], false, false);

                f16x8 wv  = *(const f16x8*)(lds + OFF_WV + kt * 512 + lane * 8);
                f16x8 wc0 = *(const f16x8*)(lds + OFF_WC + (0 * 7 + kt) * 512 + lane * 8);
                f16x8 wc1 = *(const f16x8*)(lds + OFF_WC + (1 * 7 + kt) * 512 + lane * 8);
                DV  = __builtin_amdgcn_mfma_f32_32x32x16_f16(wv,  BV.v, DV,  0, 0, 0);
                DC0 = __builtin_amdgcn_mfma_f32_32x32x16_f16(wc0, BH.v, DC0, 0, 0, 0);
                DC1 = __builtin_amdgcn_mfma_f32_32x32x16_f16(wc1, BH.v, DC1, 0, 0, 0);
            }
        }
    }

    // ---- epilogue: 16 centroids/lane, shared-rcp sigmoid pairs -------------
    // x = 5*tanh(cx) = 5 - 10/(A),  A = exp2(K*cx)+1   (K = 2*log2 e)
    // ex = x - ax = c1x - 10*(1/A);  1/A = R*B, 1/B = R*A, R = rcp(A*B)
    {
        const float c1x = 5.f - av.x;
        const float c1y = 5.f - av.y;
        float num = 0.f, den = 0.f;
        #pragma unroll
        for (int T = 0; T < 2; ++T) {
            #pragma unroll
            for (int q = 0; q < 8; ++q) {
                float cx = (T == 0) ? DC0[2 * q]     : DC1[2 * q];
                float cy = (T == 0) ? DC0[2 * q + 1] : DC1[2 * q + 1];
                float A = exp2f(2.8853900817779268f * cx) + 1.f;
                float B = exp2f(2.8853900817779268f * cy) + 1.f;
                float R = __builtin_amdgcn_rcpf(A * B);
                float ex = fmaf(-10.f, R * B, c1x);
                float ey = fmaf(-10.f, R * A, c1y);
                float dist = __builtin_amdgcn_sqrtf(fmaf(ex, ex, ey * ey));
                float wt = exp2f(-4.328085122666891f * dist);   // exp(-3 d)
                if (T == 1 && hi == 1 && q >= 6) wt = 0.f;      // n = 30, 31 pad
                num = fmaf(wt, DV[q + 8 * T], num);
                den += wt;
            }
        }
        num += __shfl_xor(num, 32);
        den += __shfl_xor(den, 32);
        if (lane < 32) out[sample] = num * __builtin_amdgcn_rcpf(den);
    }
}

extern "C" void kernel_launch(void* const* d_in, const int* in_sizes, int n_in,
                              void* d_out, int out_size, void* d_ws, size_t ws_size,
                              hipStream_t stream) {
    const float* s   = (const float*)d_in[0];
    const float* a   = (const float*)d_in[1];
    const float* W1  = (const float*)d_in[2];
    const float* b1  = (const float*)d_in[3];
    const float* W2  = (const float*)d_in[4];
    const float* b2  = (const float*)d_in[5];
    const float* L1  = (const float*)d_in[6];
    const float* bl1 = (const float*)d_in[7];
    const float* WL2 = (const float*)d_in[8];
    const float* bL2 = (const float*)d_in[9];
    float* out = (float*)d_out;
    unsigned short* ws = (unsigned short*)d_ws;

    prep_kernel<<<(TOT_HALVES + 255) / 256, 256, 0, stream>>>(
        W1, b1, W2, b2, L1, bl1, WL2, bL2, ws);

    int Btot = out_size;                 // 524288
    int grid = Btot / 256;               // 2048 WGs, 8 waves x 32 samples
    fused_kernel<<<grid, 512, 0, stream>>>(s, a, ws, out);
}

// Round 25
// 37.124 us; speedup vs baseline: 6.3742x; 6.3742x over previous
//
#include <hip/hip_runtime.h>
#include <hip/hip_fp16.h>

// ---------------------------------------------------------------------------
// Round 25 (= r24 with the launch_bounds poison removed): r23 + epilogue cut.
// r24 lesson (4th time): NEVER tighten launch_bounds — (512,8) forced a
// 64-reg budget -> 32 arch VGPR + 780MB spill -> 237µs. Reverted to (512,4).
// Epilogue cuts (isolated this round):
//   1. shared-rcp: R = rcp(A*B); 1/A = R*B, 1/B = R*A  (-16 rcp/wave)
//   2. fold 5*tanh - a:  ex = (5-ax) - 10/A, c1 hoisted per-lane
// Everything else identical to r23 (zero-mov B-frag, LDS-staged weights).
// ---------------------------------------------------------------------------

typedef _Float16 f16x8 __attribute__((ext_vector_type(8)));
typedef __fp16 fp16x2 __attribute__((ext_vector_type(2)));
typedef float f32x16 __attribute__((ext_vector_type(16)));
typedef unsigned u32x2 __attribute__((ext_vector_type(2)));

// half-index offsets inside ws / LDS
#define OFF_G1 0        // [stream 0..1][tile 0..3][lane 0..63][j 0..7]
#define OFF_WV 4096     // [kt 0..6][lane][j]
#define OFF_WC 7680     // [T 0..1][kt 0..6][lane][j]
#define TOT_HALVES 14848 // 29696 bytes

// pack two f32 -> 2xf16 (RTZ) then packed relu (v_pk_max_f16)
__device__ __forceinline__ unsigned pkrtz_relu(float a, float b) {
    fp16x2 v = __builtin_amdgcn_cvt_pkrtz(a, b);
    fp16x2 z = {(__fp16)0.f, (__fp16)0.f};
    fp16x2 r = __builtin_elementwise_max(v, z);
    union { fp16x2 v; unsigned u; } U;
    U.v = r;
    return U.u;
}
__device__ __forceinline__ unsigned pk_rne(float a, float b) {
    union { __half h[2]; unsigned u; } U;
    U.h[0] = __float2half(a);
    U.h[1] = __float2half(b);
    return U.u;
}

// ---------------- prologue: build fragment-layout weights in ws (f16) ------
__global__ __launch_bounds__(256) void prep_kernel(
    const float* __restrict__ W1, const float* __restrict__ b1,
    const float* __restrict__ W2, const float* __restrict__ b2,
    const float* __restrict__ L1, const float* __restrict__ bl1,
    const float* __restrict__ WL2, const float* __restrict__ bL2,
    unsigned short* __restrict__ ws)
{
    int idx = blockIdx.x * 256 + threadIdx.x;
    if (idx >= TOT_HALVES) return;
    float val = 0.f;

    if (idx < OFF_WV) {
        // GEMM1'' A: [r][t][ln][j]; row c = 32t + (ln&31), k = (ln>>5)*8+j
        int r = idx >> 11, t = (idx >> 9) & 3;
        int ln = (idx >> 3) & 63, j = idx & 7;
        int c = 32 * t + (ln & 31);
        int k = (ln >> 5) * 8 + j;
        const float* W  = (r == 0) ? W1 : L1;
        const float* bb = (r == 0) ? b1 : bl1;
        if (c < 100)       val = (k < 10) ? W[k * 100 + c] : ((k == 10) ? bb[c] : 0.f);
        else if (c == 100) val = (k == 10) ? 1.f : 0.f;    // h[100]=1 bias unit
    } else if (idx < OFF_WC) {
        // GEMM2'' value A: row v -> n = (v&0x19)|((v&4)>>1)|((v&2)<<1)
        // k-slot relabel: j -> pj = (j&1)|((j&2)<<1)|((j&4)>>1)
        int i = idx - OFF_WV;
        int kt = i >> 9, ln = (i >> 3) & 63, j = i & 7;
        int pj = (j & 1) | ((j & 2) << 1) | ((j & 4) >> 1);
        int v = ln & 31;
        int n = (v & 0x19) | ((v & 4) >> 1) | ((v & 2) << 1);
        int k = kt * 16 + (ln >> 5) * 8 + pj;
        if (n < 30) val = (k < 100) ? W2[k * 30 + n] : ((k == 100) ? b2[n] : 0.f);
    } else {
        // GEMM2'' centroid A: [T][kt][ln][j]; row -> (n = 16T + row>>1, d = row&1)
        int i = idx - OFF_WC;
        int T = i / 3584, rem = i % 3584;
        int kt = rem >> 9, ln = (rem >> 3) & 63, j = rem & 7;
        int pj = (j & 1) | ((j & 2) << 1) | ((j & 4) >> 1);
        int row = ln & 31;
        int n = 16 * T + (row >> 1), d = row & 1;
        int k = kt * 16 + (ln >> 5) * 8 + pj;
        if (n < 30) val = (k < 100) ? WL2[(n * 100 + k) * 2 + d]
                                    : ((k == 100) ? bL2[n * 2 + d] : 0.f);
    }
    union { __half h; unsigned short u; } cv;
    cv.h = __float2half(val);            // RNE
    ws[idx] = cv.u;
}

// ---------------- main fused kernel (LDS-staged weights, 512 thr) ----------
__global__ __launch_bounds__(512, 4) void fused_kernel(
    const float* __restrict__ s, const float* __restrict__ a,
    const unsigned short* __restrict__ ws, float* __restrict__ out)
{
    __shared__ unsigned short lds[TOT_HALVES];
    const int tid  = threadIdx.x;
    const int lane = tid & 63;
    const int wave = tid >> 6;             // 0..7
    const int m32  = lane & 31;
    const int hi   = lane >> 5;
    const int sample = blockIdx.x * 256 + wave * 32 + m32;

    // ---- stage ws -> LDS (16B chunks, 4 iters) + barrier -------------------
    {
        const int4* g4 = (const int4*)ws;
        int4* l4 = (int4*)lds;
        for (int i = tid; i < TOT_HALVES / 8; i += 512) l4[i] = g4[i];
    }

    union Frag { f16x8 v; unsigned u[4]; u32x2 p[2]; };
    const f32x16 z16 = {0,0,0,0, 0,0,0,0, 0,0,0,0, 0,0,0,0};

    // ---- s^T B-frag (overlaps staging latency): col = m32, k = hi*8+j ------
    f16x8 sf;
    {
        Frag H;
        H.u[0] = 0; H.u[1] = 0; H.u[2] = 0; H.u[3] = 0;
        const float2* p = (const float2*)(s + (size_t)sample * 10);
        if (hi == 0) {
            float2 q0 = p[0], q1 = p[1], q2 = p[2], q3 = p[3];
            H.u[0] = pk_rne(q0.x, q0.y);
            H.u[1] = pk_rne(q1.x, q1.y);
            H.u[2] = pk_rne(q2.x, q2.y);
            H.u[3] = pk_rne(q3.x, q3.y);
        } else {
            float2 q4 = p[4];
            H.u[0] = pk_rne(q4.x, q4.y);     // k = 8, 9
            H.u[1] = 0x00003C00u;            // k = 10 -> f16 1.0 (bias row)
        }
        sf = H.v;
    }
    // prefetch a for the epilogue (hide HBM latency under the body)
    float2 av = ((const float2*)a)[sample];

    __syncthreads();

    f32x16 DV = z16, DC0 = z16, DC1 = z16;

    #pragma unroll
    for (int t = 0; t < 4; ++t) {
        // ---- GEMM1'' tile t, both streams (LDS b128 reads) -----------------
        f16x8 aV = *(const f16x8*)(lds + OFF_G1 + (0 * 4 + t) * 512 + lane * 8);
        f16x8 aH = *(const f16x8*)(lds + OFF_G1 + (1 * 4 + t) * 512 + lane * 8);
        f32x16 dv = __builtin_amdgcn_mfma_f32_32x32x16_f16(aV, sf, z16, 0, 0, 0);
        f32x16 dh = __builtin_amdgcn_mfma_f32_32x32x16_f16(aH, sf, z16, 0, 0, 0);

        unsigned qv[8], qh[8];
        #pragma unroll
        for (int q = 0; q < 8; ++q) {
            qv[q] = pkrtz_relu(dv[2 * q], dv[2 * q + 1]);
            qh[q] = pkrtz_relu(dh[2 * q], dh[2 * q + 1]);
        }

        // ---- consume kt = 2t (+1): permlane exchange + GEMM2'' -------------
        // B-frag = concat(sv0, sv1): zero-mov (weights k-relabeled in prep)
        #pragma unroll
        for (int half = 0; half < 2; ++half) {
            const int kt = 2 * t + half;
            if (kt < 7) {
                const int b = half * 4;
                Frag BV, BH;
                BV.p[0] = __builtin_amdgcn_permlane32_swap(qv[b+0], qv[b+2], false, false);
                BV.p[1] = __builtin_amdgcn_permlane32_swap(qv[b+1], qv[b+3], false, false);
                BH.p[0] = __builtin_amdgcn_permlane32_swap(qh[b+0], qh[b+2], false, false);
                BH.p[1] = __builtin_amdgcn_permlane32_swap(qh[b+1], qh[b+3], false, false);

                f16x8 wv  = *(const f16x8*)(lds + OFF_WV + kt * 512 + lane * 8);
                f16x8 wc0 = *(const f16x8*)(lds + OFF_WC + (0 * 7 + kt) * 512 + lane * 8);
                f16x8 wc1 = *(const f16x8*)(lds + OFF_WC + (1 * 7 + kt) * 512 + lane * 8);
                DV  = __builtin_amdgcn_mfma_f32_32x32x16_f16(wv,  BV.v, DV,  0, 0, 0);
                DC0 = __builtin_amdgcn_mfma_f32_32x32x16_f16(wc0, BH.v, DC0, 0, 0, 0);
                DC1 = __builtin_amdgcn_mfma_f32_32x32x16_f16(wc1, BH.v, DC1, 0, 0, 0);
            }
        }
    }

    // ---- epilogue: 16 centroids/lane, shared-rcp sigmoid pairs -------------
    // x = 5*tanh(cx) = 5 - 10/A,  A = exp2(K*cx)+1   (K = 2*log2 e)
    // ex = x - ax = (5-ax) - 10*(1/A);  1/A = R*B, 1/B = R*A, R = rcp(A*B)
    {
        const float c1x = 5.f - av.x;
        const float c1y = 5.f - av.y;
        float num = 0.f, den = 0.f;
        #pragma unroll
        for (int T = 0; T < 2; ++T) {
            #pragma unroll
            for (int q = 0; q < 8; ++q) {
                float cx = (T == 0) ? DC0[2 * q]     : DC1[2 * q];
                float cy = (T == 0) ? DC0[2 * q + 1] : DC1[2 * q + 1];
                float A = exp2f(2.8853900817779268f * cx) + 1.f;
                float B = exp2f(2.8853900817779268f * cy) + 1.f;
                float R = __builtin_amdgcn_rcpf(A * B);
                float ex = fmaf(-10.f, R * B, c1x);
                float ey = fmaf(-10.f, R * A, c1y);
                float dist = __builtin_amdgcn_sqrtf(fmaf(ex, ex, ey * ey));
                float wt = exp2f(-4.328085122666891f * dist);   // exp(-3 d)
                if (T == 1 && hi == 1 && q >= 6) wt = 0.f;      // n = 30, 31 pad
                num = fmaf(wt, DV[q + 8 * T], num);
                den += wt;
            }
        }
        num += __shfl_xor(num, 32);
        den += __shfl_xor(den, 32);
        if (lane < 32) out[sample] = num * __builtin_amdgcn_rcpf(den);
    }
}

extern "C" void kernel_launch(void* const* d_in, const int* in_sizes, int n_in,
                              void* d_out, int out_size, void* d_ws, size_t ws_size,
                              hipStream_t stream) {
    const float* s   = (const float*)d_in[0];
    const float* a   = (const float*)d_in[1];
    const float* W1  = (const float*)d_in[2];
    const float* b1  = (const float*)d_in[3];
    const float* W2  = (const float*)d_in[4];
    const float* b2  = (const float*)d_in[5];
    const float* L1  = (const float*)d_in[6];
    const float* bl1 = (const float*)d_in[7];
    const float* WL2 = (const float*)d_in[8];
    const float* bL2 = (const float*)d_in[9];
    float* out = (float*)d_out;
    unsigned short* ws = (unsigned short*)d_ws;

    prep_kernel<<<(TOT_HALVES + 255) / 256, 256, 0, stream>>>(
        W1, b1, W2, b2, L1, bl1, WL2, bL2, ws);

    int Btot = out_size;                 // 524288
    int grid = Btot / 256;               // 2048 WGs, 8 waves x 32 samples
    fused_kernel<<<grid, 512, 0, stream>>>(s, a, ws, out);
}